// Round 3
// baseline (159.997 us; speedup 1.0000x reference)
//
#include <hip/hip_runtime.h>
#include <hip/hip_fp16.h>

#define B_   2
#define T_   256
#define P_   12
#define C_   512
#define H_   8
#define HKV_ 2
#define D_   64
#define S_   (T_ * P_)   // 3072
#define M_   (B_ * S_)   // 6144
#define NQKV 768         // 512 q + 128 k + 128 v

typedef _Float16 half8_t __attribute__((ext_vector_type(8)));
typedef _Float16 half4_t __attribute__((ext_vector_type(4)));
typedef _Float16 half2_t __attribute__((ext_vector_type(2)));
typedef float    float4_t __attribute__((ext_vector_type(4)));

#if __has_builtin(__builtin_amdgcn_exp2f)
#define EXP2(x) __builtin_amdgcn_exp2f(x)
#else
#define EXP2(x) __expf((x) * 0.69314718f)
#endif

#define SOFT_SHIFT 20.0f
// shift baked into accumulator init: clamp moves from 35.5 to 15.5
#define SOFT_CLAMP2 15.5f
#define QSCALE (0.125f * 1.44269504f)

// ---------------------------------------------------------------------------
// Kernel 0: prep — cast hs to f16; build transposed f16 weights
// ---------------------------------------------------------------------------
__global__ __launch_bounds__(256) void prep_kernel(
    const float* __restrict__ hs,
    const float* __restrict__ Wq, const float* __restrict__ Wk,
    const float* __restrict__ Wv, const float* __restrict__ Wo,
    _Float16* __restrict__ hs16,      // [M][512]
    _Float16* __restrict__ wcatT,     // [768][512]
    _Float16* __restrict__ woT)       // [512][512]
{
    const int blk = blockIdx.x;
    const int tid = threadIdx.x;

    if (blk < 160) {
        // transpose-cast one 64x64 tile
        __shared__ __attribute__((aligned(16))) _Float16 Ts[64][72];
        int t, K;
        const float* src; int srcN, col0; _Float16* dst;
        if (blk < 96) { t = blk; K = 512; dst = wcatT;
            int nt = t / 8;            // 12 n-tiles
            int kt = t % 8;
            int n0 = nt * 64, k0 = kt * 64;
            if (n0 < 512)      { src = Wq; srcN = 512; col0 = n0; }
            else if (n0 < 640) { src = Wk; srcN = 128; col0 = n0 - 512; }
            else               { src = Wv; srcN = 128; col0 = n0 - 640; }
#pragma unroll
            for (int i = 0; i < 4; ++i) {
                int row = i * 16 + (tid >> 4);          // k within tile
                int cg  = tid & 15;                     // n group
                float4_t v = *(const float4_t*)(src + (size_t)(k0 + row) * srcN + col0 + cg * 4);
                Ts[cg * 4 + 0][row] = (_Float16)v[0];
                Ts[cg * 4 + 1][row] = (_Float16)v[1];
                Ts[cg * 4 + 2][row] = (_Float16)v[2];
                Ts[cg * 4 + 3][row] = (_Float16)v[3];
            }
            __syncthreads();
#pragma unroll
            for (int i = 0; i < 2; ++i) {
                int seg = i * 256 + tid;
                int row = seg >> 3, s = seg & 7;        // row = n within tile
                *(half8_t*)(dst + (size_t)(n0 + row) * K + k0 + s * 8) =
                    *(const half8_t*)&Ts[row][s * 8];
            }
        } else { t = blk - 96; K = 512; dst = woT;
            int nt = t / 8, kt = t % 8;
            int n0 = nt * 64, k0 = kt * 64;
#pragma unroll
            for (int i = 0; i < 4; ++i) {
                int row = i * 16 + (tid >> 4);
                int cg  = tid & 15;
                float4_t v = *(const float4_t*)(Wo + (size_t)(k0 + row) * 512 + n0 + cg * 4);
                Ts[cg * 4 + 0][row] = (_Float16)v[0];
                Ts[cg * 4 + 1][row] = (_Float16)v[1];
                Ts[cg * 4 + 2][row] = (_Float16)v[2];
                Ts[cg * 4 + 3][row] = (_Float16)v[3];
            }
            __syncthreads();
#pragma unroll
            for (int i = 0; i < 2; ++i) {
                int seg = i * 256 + tid;
                int row = seg >> 3, s = seg & 7;
                *(half8_t*)(dst + (size_t)(n0 + row) * K + k0 + s * 8) =
                    *(const half8_t*)&Ts[row][s * 8];
            }
        }
    } else {
        // hs cast: 192 blocks x 16 iters x 256 threads x float4
        int base = (blk - 160) * 4096;
#pragma unroll
        for (int i = 0; i < 16; ++i) {
            int f4 = base + i * 256 + tid;              // 0..786431
            float4_t v = *(const float4_t*)(hs + (size_t)f4 * 4);
            half4_t hv;
            hv[0] = (_Float16)v[0]; hv[1] = (_Float16)v[1];
            hv[2] = (_Float16)v[2]; hv[3] = (_Float16)v[3];
            *(half4_t*)(hs16 + (size_t)f4 * 4) = hv;
        }
    }
}

// ---------------------------------------------------------------------------
// Kernel 1: fused QKV GEMM. hs16(M x 512) @ WcatT^T -> q/k/v buffers.
// ---------------------------------------------------------------------------
__global__ __launch_bounds__(256) void qkv_kernel(
    const _Float16* __restrict__ A,      // [M][512]
    const _Float16* __restrict__ WT,     // [768][512]
    const float* __restrict__ pitch,     // [128][64]
    _Float16* __restrict__ qb,           // [B][8][S][64]
    _Float16* __restrict__ kb,           // [B][2][S][64]
    _Float16* __restrict__ vb)           // [B][2][64][S]
{
    const int m0   = blockIdx.x * 64;
    const int n0   = blockIdx.y * 64;
    const int tid  = threadIdx.x;
    const int wave = tid >> 6;
    const int lane = tid & 63;
    const int ln   = lane & 15;
    const int quad = lane >> 4;

    __shared__ __attribute__((aligned(16))) _Float16 As[64][72];
    __shared__ __attribute__((aligned(16))) _Float16 Bs[64][72];

    float4_t acc[4];
#pragma unroll
    for (int nt = 0; nt < 4; ++nt) acc[nt] = (float4_t){0.f, 0.f, 0.f, 0.f};

    const int srow = tid >> 3;   // shared by both i=0 row base
    const int ss   = tid & 7;

    half8_t ar[2], br[2];
#pragma unroll
    for (int i = 0; i < 2; ++i) {
        int row = i * 32 + srow;
        ar[i] = *(const half8_t*)&A [(size_t)(m0 + row) * 512 + ss * 8];
        br[i] = *(const half8_t*)&WT[(size_t)(n0 + row) * 512 + ss * 8];
    }

    for (int k0 = 0; k0 < 512; k0 += 64) {
        __syncthreads();
#pragma unroll
        for (int i = 0; i < 2; ++i) {
            int row = i * 32 + srow;
            *(half8_t*)&As[row][ss * 8] = ar[i];
            *(half8_t*)&Bs[row][ss * 8] = br[i];
        }
        __syncthreads();

        if (k0 + 64 < 512) {
#pragma unroll
            for (int i = 0; i < 2; ++i) {
                int row = i * 32 + srow;
                ar[i] = *(const half8_t*)&A [(size_t)(m0 + row) * 512 + k0 + 64 + ss * 8];
                br[i] = *(const half8_t*)&WT[(size_t)(n0 + row) * 512 + k0 + 64 + ss * 8];
            }
        }

#pragma unroll
        for (int ks = 0; ks < 2; ++ks) {
            half8_t afrag = *(const half8_t*)&As[wave * 16 + ln][ks * 32 + quad * 8];
#pragma unroll
            for (int nt = 0; nt < 4; ++nt) {
                half8_t bfrag = *(const half8_t*)&Bs[nt * 16 + ln][ks * 32 + quad * 8];
                acc[nt] = __builtin_amdgcn_mfma_f32_16x16x32_f16(afrag, bfrag, acc[nt], 0, 0, 0);
            }
        }
    }

    // epilogue: region is uniform per block (n0 multiple of 64)
    const int region = (n0 < 512) ? 0 : (n0 < 640 ? 1 : 2);
#pragma unroll
    for (int nt = 0; nt < 4; ++nt) {
        int n = n0 + nt * 16 + ln;
#pragma unroll
        for (int r = 0; r < 4; ++r) {
            int m = m0 + wave * 16 + quad * 4 + r;
            int b = m / S_;
            int s = m - b * S_;
            int p = s % P_;
            float v = acc[nt][r];
            if (region == 0) {
                int h = n >> 6, dd = n & 63;
                v = (v + pitch[p * 64 + dd]) * QSCALE;
                qb[(((size_t)(b * H_ + h)) * S_ + s) * 64 + dd] = (_Float16)v;
            } else if (region == 1) {
                int nn = n - 512, h = nn >> 6, dd = nn & 63;
                v = v + pitch[p * 64 + dd];
                kb[(((size_t)(b * HKV_ + h)) * S_ + s) * 64 + dd] = (_Float16)v;
            } else {
                int nn = n - 640, h = nn >> 6, dd = nn & 63;
                vb[(((size_t)(b * HKV_ + h)) * 64 + dd) * S_ + s] = (_Float16)v;
            }
        }
    }
}

// ---------------------------------------------------------------------------
// Kernel 2: flash attention, 8 waves, 128-key tiles, in-register P.
// QK^T computed SWAPPED: mfma(K, Q) -> D[key][q], so each lane holds a full
// 8-key P slice for one q (q = ln). P feeds PV's A-operand directly from
// registers under permutation sigma(quad*8+j) = 16*(j>>2) + 4*quad + (j&3);
// sigma is absorbed into V's LDS layout at staging (two half4 writes).
// No Ps buffer, no P LDS round-trip. Pads = 72 (stride 144B): all Ks/VT
// reads+writes are bank-ideal (row contributes 4*(row&7) to bank index).
// ---------------------------------------------------------------------------
__global__ __launch_bounds__(512) void attn_kernel(
    const _Float16* __restrict__ qbuf,  // [B][H][S][64]
    const _Float16* __restrict__ kbuf,  // [B][HKV][S][64]
    const _Float16* __restrict__ vtb,   // [B][HKV][64][S]
    _Float16* __restrict__ ob)          // [B*S][512]
{
    const int qblk = blockIdx.x;
    const int bh   = blockIdx.y;
    const int b    = bh >> 3;
    const int h    = bh & 7;
    const int hkv  = h >> 2;
    const int tid  = threadIdx.x;
    const int w    = tid >> 6;          // 0..7
    const int lane = tid & 63;
    const int ln   = lane & 15;
    const int quad = lane >> 4;

    const _Float16* Q  = qbuf + ((size_t)(b * H_ + h)) * S_ * 64;
    const _Float16* K  = kbuf + ((size_t)(b * HKV_ + hkv)) * S_ * 64;
    const _Float16* Vt = vtb  + ((size_t)(b * HKV_ + hkv)) * 64 * S_;

    __shared__ __attribute__((aligned(16))) _Float16 Ks[128][72];    // 18432 B
    __shared__ __attribute__((aligned(16))) _Float16 VT[2][64][72];  // 18432 B

    const int qbase = qblk * 64 + (w & 3) * 16;
    const int kk0   = (w >> 2) * 32;

    half8_t qfrag[2];
#pragma unroll
    for (int ks = 0; ks < 2; ++ks)
        qfrag[ks] = *(const half8_t*)&Q[(size_t)(qbase + ln) * 64 + ks * 32 + quad * 8];

    float4_t o[4];
#pragma unroll
    for (int nt = 0; nt < 4; ++nt) o[nt] = (float4_t){0.f, 0.f, 0.f, 0.f};
    float lsum = 0.f;                     // denominator partial for q = qbase+ln

    // staging: K natural rows; V sigma-interleaved (two half4 writes per seg)
    const int j = tid >> 3, s = tid & 7;  // j: 0..63
    const int vbase = 32 * (s >> 2) + 16 * (s & 1) + 4 * ((s >> 1) & 1);

    half8_t kr0, kr1, vr0, vr1;
    kr0 = *(const half8_t*)&K[(size_t)j * 64 + s * 8];
    kr1 = *(const half8_t*)&K[(size_t)(64 + j) * 64 + s * 8];
    vr0 = *(const half8_t*)&Vt[(size_t)j * S_ + s * 8];
    vr1 = *(const half8_t*)&Vt[(size_t)j * S_ + 64 + s * 8];

    for (int kt = 0; kt < S_; kt += 128) {
        __syncthreads();
        *(half8_t*)&Ks[j][s * 8]      = kr0;
        *(half8_t*)&Ks[j + 64][s * 8] = kr1;
        {
            half4_t lo0 = __builtin_shufflevector(vr0, vr0, 0, 1, 2, 3);
            half4_t hi0 = __builtin_shufflevector(vr0, vr0, 4, 5, 6, 7);
            half4_t lo1 = __builtin_shufflevector(vr1, vr1, 0, 1, 2, 3);
            half4_t hi1 = __builtin_shufflevector(vr1, vr1, 4, 5, 6, 7);
            *(half4_t*)&VT[0][j][vbase]     = lo0;
            *(half4_t*)&VT[0][j][vbase + 8] = hi0;
            *(half4_t*)&VT[1][j][vbase]     = lo1;
            *(half4_t*)&VT[1][j][vbase + 8] = hi1;
        }
        __syncthreads();

        if (kt + 128 < S_) {
            kr0 = *(const half8_t*)&K[(size_t)(kt + 128 + j) * 64 + s * 8];
            kr1 = *(const half8_t*)&K[(size_t)(kt + 128 + 64 + j) * 64 + s * 8];
            vr0 = *(const half8_t*)&Vt[(size_t)j * S_ + kt + 128 + s * 8];
            vr1 = *(const half8_t*)&Vt[(size_t)j * S_ + kt + 128 + 64 + s * 8];
        }

#pragma unroll
        for (int h2 = 0; h2 < 2; ++h2) {
            const int kbase = h2 * 64 + kk0;

            // QK^T swapped: D[key][q]. lane: q = ln, keys kbase + 4*quad+rr (+16 for c=1)
            float4_t sf0 = (float4_t){-SOFT_SHIFT, -SOFT_SHIFT, -SOFT_SHIFT, -SOFT_SHIFT};
            float4_t sf1 = (float4_t){-SOFT_SHIFT, -SOFT_SHIFT, -SOFT_SHIFT, -SOFT_SHIFT};
            __builtin_amdgcn_s_setprio(1);
#pragma unroll
            for (int ks = 0; ks < 2; ++ks) {
                half8_t kf0 = *(const half8_t*)&Ks[kbase + ln][ks * 32 + quad * 8];
                half8_t kf1 = *(const half8_t*)&Ks[kbase + 16 + ln][ks * 32 + quad * 8];
                sf0 = __builtin_amdgcn_mfma_f32_16x16x32_f16(kf0, qfrag[ks], sf0, 0, 0, 0);
                sf1 = __builtin_amdgcn_mfma_f32_16x16x32_f16(kf1, qfrag[ks], sf1, 0, 0, 0);
            }
            __builtin_amdgcn_s_setprio(0);

            // softmax: exp in-register, pack directly into PV A-frag (j = 4c + rr)
            float e00 = EXP2(fminf(sf0[0], SOFT_CLAMP2));
            float e01 = EXP2(fminf(sf0[1], SOFT_CLAMP2));
            float e02 = EXP2(fminf(sf0[2], SOFT_CLAMP2));
            float e03 = EXP2(fminf(sf0[3], SOFT_CLAMP2));
            float e10 = EXP2(fminf(sf1[0], SOFT_CLAMP2));
            float e11 = EXP2(fminf(sf1[1], SOFT_CLAMP2));
            float e12 = EXP2(fminf(sf1[2], SOFT_CLAMP2));
            float e13 = EXP2(fminf(sf1[3], SOFT_CLAMP2));
            lsum += ((e00 + e01) + (e02 + e03)) + ((e10 + e11) + (e12 + e13));
            half8_t pf;
            pf[0] = (_Float16)e00; pf[1] = (_Float16)e01;
            pf[2] = (_Float16)e02; pf[3] = (_Float16)e03;
            pf[4] = (_Float16)e10; pf[5] = (_Float16)e11;
            pf[6] = (_Float16)e12; pf[7] = (_Float16)e13;

            // PV: O(16q x 64d) += P(16q x 32k) . V(32k x 64d); V is sigma-laid-out
            __builtin_amdgcn_s_setprio(1);
#pragma unroll
            for (int nt = 0; nt < 4; ++nt) {
                half8_t vf = *(const half8_t*)&VT[h2][nt * 16 + ln][kk0 + quad * 8];
                o[nt] = __builtin_amdgcn_mfma_f32_16x16x32_f16(pf, vf, o[nt], 0, 0, 0);
            }
            __builtin_amdgcn_s_setprio(0);
        }
    }

    // l reduction: lane holds lsum for q = qbase+ln over its quad's keys.
    // Reduce across quads, publish per-wave l[16], then combine (w, w+4).
    __syncthreads();
    lsum += __shfl_xor(lsum, 16);
    lsum += __shfl_xor(lsum, 32);
    float* Lb = (float*)&VT[0][0][0];        // 128 floats, VT dead
    if (quad == 0) Lb[w * 16 + ln] = lsum;
    if (w >= 4) {
        float* od = (float*)&Ks[0][0] + (w - 4) * 1024;   // 4096 floats <= Ks
#pragma unroll
        for (int nt = 0; nt < 4; ++nt)
            *(float4_t*)&od[lane * 16 + nt * 4] = o[nt];
    }
    __syncthreads();
    if (w < 4) {
        const float* os = (const float*)&Ks[0][0] + w * 1024;
#pragma unroll
        for (int rr = 0; rr < 4; ++rr) {
            int t = quad * 4 + rr;
            float l = Lb[w * 16 + t] + Lb[(w + 4) * 16 + t];
            float inv = 1.0f / l;
            int qg = qbase + t;
            size_t base = ((size_t)(b * S_ + qg)) * 512 + h * 64;
#pragma unroll
            for (int nt = 0; nt < 4; ++nt) {
                float vsum = o[nt][rr] + os[lane * 16 + nt * 4 + rr];
                ob[base + nt * 16 + ln] = (_Float16)(vsum * inv);
            }
        }
    }
}

// ---------------------------------------------------------------------------
// Kernel 3: O(f16, M x 512) @ Wo -> fp32 out, using pre-transposed woT f16.
// ---------------------------------------------------------------------------
__global__ __launch_bounds__(256) void proj_out_kernel(
    const _Float16* __restrict__ A,      // [M][512]
    const _Float16* __restrict__ WT,     // [512][512]
    float* __restrict__ outp)            // [M][512]
{
    const int m0   = blockIdx.x * 64;
    const int n0   = blockIdx.y * 64;
    const int tid  = threadIdx.x;
    const int wave = tid >> 6;
    const int lane = tid & 63;
    const int ln   = lane & 15;
    const int quad = lane >> 4;

    __shared__ __attribute__((aligned(16))) _Float16 As[64][72];
    __shared__ __attribute__((aligned(16))) _Float16 Bs[64][72];

    float4_t acc[4];
#pragma unroll
    for (int nt = 0; nt < 4; ++nt) acc[nt] = (float4_t){0.f, 0.f, 0.f, 0.f};

    const int srow = tid >> 3;
    const int ss   = tid & 7;

    half8_t ar[2], br[2];
#pragma unroll
    for (int i = 0; i < 2; ++i) {
        int row = i * 32 + srow;
        ar[i] = *(const half8_t*)&A [(size_t)(m0 + row) * 512 + ss * 8];
        br[i] = *(const half8_t*)&WT[(size_t)(n0 + row) * 512 + ss * 8];
    }

    for (int k0 = 0; k0 < 512; k0 += 64) {
        __syncthreads();
#pragma unroll
        for (int i = 0; i < 2; ++i) {
            int row = i * 32 + srow;
            *(half8_t*)&As[row][ss * 8] = ar[i];
            *(half8_t*)&Bs[row][ss * 8] = br[i];
        }
        __syncthreads();

        if (k0 + 64 < 512) {
#pragma unroll
            for (int i = 0; i < 2; ++i) {
                int row = i * 32 + srow;
                ar[i] = *(const half8_t*)&A [(size_t)(m0 + row) * 512 + k0 + 64 + ss * 8];
                br[i] = *(const half8_t*)&WT[(size_t)(n0 + row) * 512 + k0 + 64 + ss * 8];
            }
        }

#pragma unroll
        for (int ks = 0; ks < 2; ++ks) {
            half8_t afrag = *(const half8_t*)&As[wave * 16 + ln][ks * 32 + quad * 8];
#pragma unroll
            for (int nt = 0; nt < 4; ++nt) {
                half8_t bfrag = *(const half8_t*)&Bs[nt * 16 + ln][ks * 32 + quad * 8];
                acc[nt] = __builtin_amdgcn_mfma_f32_16x16x32_f16(afrag, bfrag, acc[nt], 0, 0, 0);
            }
        }
    }

#pragma unroll
    for (int nt = 0; nt < 4; ++nt) {
        int n = n0 + nt * 16 + ln;
#pragma unroll
        for (int r = 0; r < 4; ++r) {
            int m = m0 + wave * 16 + quad * 4 + r;
            outp[(size_t)m * 512 + n] = acc[nt][r];
        }
    }
}

// ---------------------------------------------------------------------------
extern "C" void kernel_launch(void* const* d_in, const int* in_sizes, int n_in,
                              void* d_out, int out_size, void* d_ws, size_t ws_size,
                              hipStream_t stream) {
    const float* hs    = (const float*)d_in[0];
    const float* Wq    = (const float*)d_in[1];
    const float* Wk    = (const float*)d_in[2];
    const float* Wv    = (const float*)d_in[3];
    const float* Wo    = (const float*)d_in[4];
    const float* pitch = (const float*)d_in[5];
    float* out = (float*)d_out;

    // ws layout (f16 elements). o_buf aliases hs16 (hs16 dead after qkv_kernel).
    _Float16* hs16  = (_Float16*)d_ws;                           // M*512 = 3,145,728
    _Float16* o_buf = hs16;                                      // alias
    _Float16* q_buf = hs16 + (size_t)M_ * 512;                   // 3,145,728
    _Float16* k_buf = q_buf + (size_t)B_ * H_ * S_ * 64;         //   786,432
    _Float16* v_buf = k_buf + (size_t)B_ * HKV_ * S_ * 64;       //   786,432
    _Float16* wcatT = v_buf + (size_t)B_ * HKV_ * S_ * 64;       //   393,216
    _Float16* woT   = wcatT + (size_t)NQKV * 512;                //   262,144

    prep_kernel<<<352, 256, 0, stream>>>(hs, Wq, Wk, Wv, Wo, hs16, wcatT, woT);
    qkv_kernel<<<dim3(M_ / 64, NQKV / 64), 256, 0, stream>>>(hs16, wcatT, pitch, q_buf, k_buf, v_buf);
    attn_kernel<<<dim3(S_ / 64, B_ * H_), 512, 0, stream>>>(q_buf, k_buf, v_buf, o_buf);
    proj_out_kernel<<<dim3(M_ / 64, 8), 256, 0, stream>>>(o_buf, woT, out);
}

// Round 4
// 157.032 us; speedup vs baseline: 1.0189x; 1.0189x over previous
//
#include <hip/hip_runtime.h>
#include <hip/hip_fp16.h>

#define B_   2
#define T_   256
#define P_   12
#define C_   512
#define H_   8
#define HKV_ 2
#define D_   64
#define S_   (T_ * P_)   // 3072
#define M_   (B_ * S_)   // 6144
#define NQKV 768         // 512 q + 128 k + 128 v

typedef _Float16 half8_t __attribute__((ext_vector_type(8)));
typedef _Float16 half4_t __attribute__((ext_vector_type(4)));
typedef _Float16 half2_t __attribute__((ext_vector_type(2)));
typedef float    float4_t __attribute__((ext_vector_type(4)));

#if __has_builtin(__builtin_amdgcn_exp2f)
#define EXP2(x) __builtin_amdgcn_exp2f(x)
#else
#define EXP2(x) __expf((x) * 0.69314718f)
#endif

#define SOFT_SHIFT 20.0f
// shift baked into accumulator init: clamp moves from 35.5 to 15.5
#define SOFT_CLAMP2 15.5f
#define QSCALE (0.125f * 1.44269504f)

// ---------------------------------------------------------------------------
// Kernel 0: prep — cast hs to f16; build transposed f16 weights
// ---------------------------------------------------------------------------
__global__ __launch_bounds__(256) void prep_kernel(
    const float* __restrict__ hs,
    const float* __restrict__ Wq, const float* __restrict__ Wk,
    const float* __restrict__ Wv, const float* __restrict__ Wo,
    _Float16* __restrict__ hs16,      // [M][512]
    _Float16* __restrict__ wcatT,     // [768][512]
    _Float16* __restrict__ woT)       // [512][512]
{
    const int blk = blockIdx.x;
    const int tid = threadIdx.x;

    if (blk < 160) {
        // transpose-cast one 64x64 tile
        __shared__ __attribute__((aligned(16))) _Float16 Ts[64][72];
        int t, K;
        const float* src; int srcN, col0; _Float16* dst;
        if (blk < 96) { t = blk; K = 512; dst = wcatT;
            int nt = t / 8;            // 12 n-tiles
            int kt = t % 8;
            int n0 = nt * 64, k0 = kt * 64;
            if (n0 < 512)      { src = Wq; srcN = 512; col0 = n0; }
            else if (n0 < 640) { src = Wk; srcN = 128; col0 = n0 - 512; }
            else               { src = Wv; srcN = 128; col0 = n0 - 640; }
#pragma unroll
            for (int i = 0; i < 4; ++i) {
                int row = i * 16 + (tid >> 4);          // k within tile
                int cg  = tid & 15;                     // n group
                float4_t v = *(const float4_t*)(src + (size_t)(k0 + row) * srcN + col0 + cg * 4);
                Ts[cg * 4 + 0][row] = (_Float16)v[0];
                Ts[cg * 4 + 1][row] = (_Float16)v[1];
                Ts[cg * 4 + 2][row] = (_Float16)v[2];
                Ts[cg * 4 + 3][row] = (_Float16)v[3];
            }
            __syncthreads();
#pragma unroll
            for (int i = 0; i < 2; ++i) {
                int seg = i * 256 + tid;
                int row = seg >> 3, s = seg & 7;        // row = n within tile
                *(half8_t*)(dst + (size_t)(n0 + row) * K + k0 + s * 8) =
                    *(const half8_t*)&Ts[row][s * 8];
            }
        } else { t = blk - 96; K = 512; dst = woT;
            int nt = t / 8, kt = t % 8;
            int n0 = nt * 64, k0 = kt * 64;
#pragma unroll
            for (int i = 0; i < 4; ++i) {
                int row = i * 16 + (tid >> 4);
                int cg  = tid & 15;
                float4_t v = *(const float4_t*)(Wo + (size_t)(k0 + row) * 512 + n0 + cg * 4);
                Ts[cg * 4 + 0][row] = (_Float16)v[0];
                Ts[cg * 4 + 1][row] = (_Float16)v[1];
                Ts[cg * 4 + 2][row] = (_Float16)v[2];
                Ts[cg * 4 + 3][row] = (_Float16)v[3];
            }
            __syncthreads();
#pragma unroll
            for (int i = 0; i < 2; ++i) {
                int seg = i * 256 + tid;
                int row = seg >> 3, s = seg & 7;
                *(half8_t*)(dst + (size_t)(n0 + row) * K + k0 + s * 8) =
                    *(const half8_t*)&Ts[row][s * 8];
            }
        }
    } else {
        // hs cast: 192 blocks x 16 iters x 256 threads x float4
        int base = (blk - 160) * 4096;
#pragma unroll
        for (int i = 0; i < 16; ++i) {
            int f4 = base + i * 256 + tid;              // 0..786431
            float4_t v = *(const float4_t*)(hs + (size_t)f4 * 4);
            half4_t hv;
            hv[0] = (_Float16)v[0]; hv[1] = (_Float16)v[1];
            hv[2] = (_Float16)v[2]; hv[3] = (_Float16)v[3];
            *(half4_t*)(hs16 + (size_t)f4 * 4) = hv;
        }
    }
}

// ---------------------------------------------------------------------------
// Kernel 1: fused QKV GEMM. hs16(M x 512) @ WcatT^T -> q/k/v buffers.
// Epilogue: single div/mod per thread; V-region transposed through LDS
// so vb stores are coalesced 16B rows (was a 2B/lane stride-6KB scatter).
// ---------------------------------------------------------------------------
__global__ __launch_bounds__(256) void qkv_kernel(
    const _Float16* __restrict__ A,      // [M][512]
    const _Float16* __restrict__ WT,     // [768][512]
    const float* __restrict__ pitch,     // [128][64]
    _Float16* __restrict__ qb,           // [B][8][S][64]
    _Float16* __restrict__ kb,           // [B][2][S][64]
    _Float16* __restrict__ vb)           // [B][2][64][S]
{
    const int m0   = blockIdx.x * 64;
    const int n0   = blockIdx.y * 64;
    const int tid  = threadIdx.x;
    const int wave = tid >> 6;
    const int lane = tid & 63;
    const int ln   = lane & 15;
    const int quad = lane >> 4;

    __shared__ __attribute__((aligned(16))) _Float16 As[64][72];
    __shared__ __attribute__((aligned(16))) _Float16 Bs[64][72];

    float4_t acc[4];
#pragma unroll
    for (int nt = 0; nt < 4; ++nt) acc[nt] = (float4_t){0.f, 0.f, 0.f, 0.f};

    const int srow = tid >> 3;   // shared by both i=0 row base
    const int ss   = tid & 7;

    half8_t ar[2], br[2];
#pragma unroll
    for (int i = 0; i < 2; ++i) {
        int row = i * 32 + srow;
        ar[i] = *(const half8_t*)&A [(size_t)(m0 + row) * 512 + ss * 8];
        br[i] = *(const half8_t*)&WT[(size_t)(n0 + row) * 512 + ss * 8];
    }

    for (int k0 = 0; k0 < 512; k0 += 64) {
        __syncthreads();
#pragma unroll
        for (int i = 0; i < 2; ++i) {
            int row = i * 32 + srow;
            *(half8_t*)&As[row][ss * 8] = ar[i];
            *(half8_t*)&Bs[row][ss * 8] = br[i];
        }
        __syncthreads();

        if (k0 + 64 < 512) {
#pragma unroll
            for (int i = 0; i < 2; ++i) {
                int row = i * 32 + srow;
                ar[i] = *(const half8_t*)&A [(size_t)(m0 + row) * 512 + k0 + 64 + ss * 8];
                br[i] = *(const half8_t*)&WT[(size_t)(n0 + row) * 512 + k0 + 64 + ss * 8];
            }
        }

#pragma unroll
        for (int ks = 0; ks < 2; ++ks) {
            half8_t afrag = *(const half8_t*)&As[wave * 16 + ln][ks * 32 + quad * 8];
#pragma unroll
            for (int nt = 0; nt < 4; ++nt) {
                half8_t bfrag = *(const half8_t*)&Bs[nt * 16 + ln][ks * 32 + quad * 8];
                acc[nt] = __builtin_amdgcn_mfma_f32_16x16x32_f16(afrag, bfrag, acc[nt], 0, 0, 0);
            }
        }
    }

    // epilogue: region is uniform per block (n0 multiple of 64).
    // b is block-uniform (64-row tiles never cross the batch boundary);
    // one % P_ per thread, incremental wrap for r.
    const int bb      = m0 / S_;
    const int s00     = m0 - bb * S_;                  // block-uniform
    const int sl_base = wave * 16 + quad * 4;          // 0..60
    const int s_base  = s00 + sl_base;
    const int p_base  = s_base % P_;

    if (n0 < 512) {
        const int h = n0 >> 6;
#pragma unroll
        for (int r = 0; r < 4; ++r) {
            int p = p_base + r; if (p >= P_) p -= P_;
            const float* pr = pitch + p * 64;
            size_t rowb = ((size_t)(bb * H_ + h) * S_ + s_base + r) * 64;
#pragma unroll
            for (int nt = 0; nt < 4; ++nt) {
                int dd = nt * 16 + ln;
                float v = (acc[nt][r] + pr[dd]) * QSCALE;
                qb[rowb + dd] = (_Float16)v;
            }
        }
    } else if (n0 < 640) {
        const int h = (n0 - 512) >> 6;
#pragma unroll
        for (int r = 0; r < 4; ++r) {
            int p = p_base + r; if (p >= P_) p -= P_;
            const float* pr = pitch + p * 64;
            size_t rowb = ((size_t)(bb * HKV_ + h) * S_ + s_base + r) * 64;
#pragma unroll
            for (int nt = 0; nt < 4; ++nt) {
                int dd = nt * 16 + ln;
                kb[rowb + dd] = (_Float16)(acc[nt][r] + pr[dd]);
            }
        }
    } else {
        // V region: no bias. Transpose 64s x 64d tile through LDS (reuse As),
        // then store coalesced rows of vb[(bh*64+dd)*S + s].
        const int h = (n0 - 640) >> 6;
        __syncthreads();
#pragma unroll
        for (int nt = 0; nt < 4; ++nt)
#pragma unroll
            for (int r = 0; r < 4; ++r)
                As[nt * 16 + ln][sl_base + r] = (_Float16)acc[nt][r];
        __syncthreads();
        const int rw = tid >> 2;            // dd row 0..63
        const int c0 = (tid & 3) * 16;      // s col group
        _Float16* dst = vb + ((size_t)(bb * HKV_ + h) * 64 + rw) * S_ + s00 + c0;
        *(half8_t*)dst       = *(const half8_t*)&As[rw][c0];
        *(half8_t*)(dst + 8) = *(const half8_t*)&As[rw][c0 + 8];
    }
}

// ---------------------------------------------------------------------------
// Kernel 2: flash attention, 8 waves (512 threads), 128-key tiles.
// Round-2 structure (best measured) with: VT split [2][64][80] (stride-80
// rows, bank-clean), and a bank-clean cross-wave combine (o-scratch stride
// 20 -> bank 4*(5*lane+nt) bijective per 8-lane phase; l as float4).
// ---------------------------------------------------------------------------
__global__ __launch_bounds__(512) void attn_kernel(
    const _Float16* __restrict__ qbuf,  // [B][H][S][64]
    const _Float16* __restrict__ kbuf,  // [B][HKV][S][64]
    const _Float16* __restrict__ vtb,   // [B][HKV][64][S]
    _Float16* __restrict__ ob)          // [B*S][512]
{
    const int qblk = blockIdx.x;
    const int bh   = blockIdx.y;
    const int b    = bh >> 3;
    const int h    = bh & 7;
    const int hkv  = h >> 2;
    const int tid  = threadIdx.x;
    const int w    = tid >> 6;          // 0..7
    const int lane = tid & 63;
    const int ln   = lane & 15;
    const int quad = lane >> 4;

    const _Float16* Q  = qbuf + ((size_t)(b * H_ + h)) * S_ * 64;
    const _Float16* K  = kbuf + ((size_t)(b * HKV_ + hkv)) * S_ * 64;
    const _Float16* Vt = vtb  + ((size_t)(b * HKV_ + hkv)) * 64 * S_;

    __shared__ __attribute__((aligned(16))) _Float16 Ks[128][80];    // 20480 B
    __shared__ __attribute__((aligned(16))) _Float16 VT[2][64][80];  // 20480 B
    __shared__ __attribute__((aligned(16))) _Float16 Ps[8][16][40];  // 10240 B

    const int qbase = qblk * 64 + (w & 3) * 16;
    const int kk0   = (w >> 2) * 32;

    half8_t qfrag[2];
#pragma unroll
    for (int ks = 0; ks < 2; ++ks)
        qfrag[ks] = *(const half8_t*)&Q[(size_t)(qbase + ln) * 64 + ks * 32 + quad * 8];

    float4_t o[4];
#pragma unroll
    for (int nt = 0; nt < 4; ++nt) o[nt] = (float4_t){0.f, 0.f, 0.f, 0.f};
    float lr[4] = {0.f, 0.f, 0.f, 0.f};

    // staging: 2 K segs + 2 V segs per thread (512 threads)
    const int j = tid >> 3, s = tid & 7;        // j: 0..63
    // key-interleave swizzle so packed half2 P writes land in natural A-frag order;
    // swz(j+64) = swz(j)+64.
    const int r0 = ((j & 1) << 4) | ((j >> 5) << 5) | ((j >> 1) & 15);

    half8_t kr0, kr1, vr0, vr1;
    kr0 = *(const half8_t*)&K[(size_t)j * 64 + s * 8];
    kr1 = *(const half8_t*)&K[(size_t)(64 + j) * 64 + s * 8];
    vr0 = *(const half8_t*)&Vt[(size_t)j * S_ + s * 8];
    vr1 = *(const half8_t*)&Vt[(size_t)j * S_ + 64 + s * 8];

    for (int kt = 0; kt < S_; kt += 128) {
        __syncthreads();
        *(half8_t*)&Ks[r0][s * 8]      = kr0;
        *(half8_t*)&Ks[r0 + 64][s * 8] = kr1;
        *(half8_t*)&VT[0][j][s * 8]    = vr0;
        *(half8_t*)&VT[1][j][s * 8]    = vr1;
        __syncthreads();

        if (kt + 128 < S_) {
            kr0 = *(const half8_t*)&K[(size_t)(kt + 128 + j) * 64 + s * 8];
            kr1 = *(const half8_t*)&K[(size_t)(kt + 128 + 64 + j) * 64 + s * 8];
            vr0 = *(const half8_t*)&Vt[(size_t)j * S_ + kt + 128 + s * 8];
            vr1 = *(const half8_t*)&Vt[(size_t)j * S_ + kt + 128 + 64 + s * 8];
        }

#pragma unroll
        for (int h2 = 0; h2 < 2; ++h2) {
            const int kb = h2 * 64 + kk0;

            // QK^T: this wave's 32 keys of this half (2 interleaved 16-tiles).
            float4_t sf[2];
            __builtin_amdgcn_s_setprio(1);
#pragma unroll
            for (int c = 0; c < 2; ++c) {
                sf[c] = (float4_t){-SOFT_SHIFT, -SOFT_SHIFT, -SOFT_SHIFT, -SOFT_SHIFT};
#pragma unroll
                for (int ks = 0; ks < 2; ++ks) {
                    half8_t kf = *(const half8_t*)&Ks[kb + c * 16 + ln][ks * 32 + quad * 8];
                    sf[c] = __builtin_amdgcn_mfma_f32_16x16x32_f16(qfrag[ks], kf, sf[c], 0, 0, 0);
                }
            }
            __builtin_amdgcn_s_setprio(0);

            // fixed-shift softmax, packed half2 P writes (cols = natural local key)
#pragma unroll
            for (int rr = 0; rr < 4; ++rr) {
                float p0 = EXP2(fminf(sf[0][rr], SOFT_CLAMP2));
                float p1 = EXP2(fminf(sf[1][rr], SOFT_CLAMP2));
                lr[rr] += p0 + p1;
                half2_t w2; w2[0] = (_Float16)p0; w2[1] = (_Float16)p1;
                *(half2_t*)&Ps[w][quad * 4 + rr][2 * ln] = w2;
            }

            // PV: O(16q x 64d) += P(16q x 32k) . V(32k x 64d)
            half8_t pf = *(const half8_t*)&Ps[w][ln][quad * 8];
            __builtin_amdgcn_s_setprio(1);
#pragma unroll
            for (int nt = 0; nt < 4; ++nt) {
                half8_t vf = *(const half8_t*)&VT[h2][nt * 16 + ln][kk0 + quad * 8];
                o[nt] = __builtin_amdgcn_mfma_f32_16x16x32_f16(pf, vf, o[nt], 0, 0, 0);
            }
            __builtin_amdgcn_s_setprio(0);
        }
    }

    // cross-wave combine: wave w and w+4 share queries, disjoint keys.
    // Bank-clean scratch: o at stride 20 (float4-aligned, bank 4*(5l+nt)),
    // l as one float4 per lane.
    __syncthreads();
    if (w >= 4) {
        float* od = (float*)&Ks[0][0] + (w - 4) * 1280;   // 4x1280 = 5120 floats = Ks
#pragma unroll
        for (int nt = 0; nt < 4; ++nt)
            *(float4_t*)&od[lane * 20 + nt * 4] = o[nt];
        float* ld = (float*)&Ps[0][0][0] + (w - 4) * 256;
        *(float4_t*)&ld[lane * 4] = (float4_t){lr[0], lr[1], lr[2], lr[3]};
    }
    __syncthreads();
    if (w < 4) {
        const float* os = (const float*)&Ks[0][0] + w * 1280;
        const float* ls = (const float*)&Ps[0][0][0] + w * 256;
        float4_t ls4 = *(const float4_t*)&ls[lane * 4];
        float4_t os4[4];
#pragma unroll
        for (int nt = 0; nt < 4; ++nt)
            os4[nt] = *(const float4_t*)&os[lane * 20 + nt * 4];
#pragma unroll
        for (int rr = 0; rr < 4; ++rr) {
            float l = lr[rr] + ls4[rr];
            l += __shfl_xor(l, 1);
            l += __shfl_xor(l, 2);
            l += __shfl_xor(l, 4);
            l += __shfl_xor(l, 8);
            float inv = 1.0f / l;
            int qg = qbase + quad * 4 + rr;
            size_t base = ((size_t)(b * S_ + qg)) * 512 + h * 64;
#pragma unroll
            for (int nt = 0; nt < 4; ++nt) {
                float vsum = o[nt][rr] + os4[nt][rr];
                ob[base + nt * 16 + ln] = (_Float16)(vsum * inv);
            }
        }
    }
}

// ---------------------------------------------------------------------------
// Kernel 3: O(f16, M x 512) @ Wo -> fp32 out, using pre-transposed woT f16.
// ---------------------------------------------------------------------------
__global__ __launch_bounds__(256) void proj_out_kernel(
    const _Float16* __restrict__ A,      // [M][512]
    const _Float16* __restrict__ WT,     // [512][512]
    float* __restrict__ outp)            // [M][512]
{
    const int m0   = blockIdx.x * 64;
    const int n0   = blockIdx.y * 64;
    const int tid  = threadIdx.x;
    const int wave = tid >> 6;
    const int lane = tid & 63;
    const int ln   = lane & 15;
    const int quad = lane >> 4;

    __shared__ __attribute__((aligned(16))) _Float16 As[64][72];
    __shared__ __attribute__((aligned(16))) _Float16 Bs[64][72];

    float4_t acc[4];
#pragma unroll
    for (int nt = 0; nt < 4; ++nt) acc[nt] = (float4_t){0.f, 0.f, 0.f, 0.f};

    const int srow = tid >> 3;
    const int ss   = tid & 7;

    half8_t ar[2], br[2];
#pragma unroll
    for (int i = 0; i < 2; ++i) {
        int row = i * 32 + srow;
        ar[i] = *(const half8_t*)&A [(size_t)(m0 + row) * 512 + ss * 8];
        br[i] = *(const half8_t*)&WT[(size_t)(n0 + row) * 512 + ss * 8];
    }

    for (int k0 = 0; k0 < 512; k0 += 64) {
        __syncthreads();
#pragma unroll
        for (int i = 0; i < 2; ++i) {
            int row = i * 32 + srow;
            *(half8_t*)&As[row][ss * 8] = ar[i];
            *(half8_t*)&Bs[row][ss * 8] = br[i];
        }
        __syncthreads();

        if (k0 + 64 < 512) {
#pragma unroll
            for (int i = 0; i < 2; ++i) {
                int row = i * 32 + srow;
                ar[i] = *(const half8_t*)&A [(size_t)(m0 + row) * 512 + k0 + 64 + ss * 8];
                br[i] = *(const half8_t*)&WT[(size_t)(n0 + row) * 512 + k0 + 64 + ss * 8];
            }
        }

#pragma unroll
        for (int ks = 0; ks < 2; ++ks) {
            half8_t afrag = *(const half8_t*)&As[wave * 16 + ln][ks * 32 + quad * 8];
#pragma unroll
            for (int nt = 0; nt < 4; ++nt) {
                half8_t bfrag = *(const half8_t*)&Bs[nt * 16 + ln][ks * 32 + quad * 8];
                acc[nt] = __builtin_amdgcn_mfma_f32_16x16x32_f16(afrag, bfrag, acc[nt], 0, 0, 0);
            }
        }
    }

#pragma unroll
    for (int nt = 0; nt < 4; ++nt) {
        int n = n0 + nt * 16 + ln;
#pragma unroll
        for (int r = 0; r < 4; ++r) {
            int m = m0 + wave * 16 + quad * 4 + r;
            outp[(size_t)m * 512 + n] = acc[nt][r];
        }
    }
}

// ---------------------------------------------------------------------------
extern "C" void kernel_launch(void* const* d_in, const int* in_sizes, int n_in,
                              void* d_out, int out_size, void* d_ws, size_t ws_size,
                              hipStream_t stream) {
    const float* hs    = (const float*)d_in[0];
    const float* Wq    = (const float*)d_in[1];
    const float* Wk    = (const float*)d_in[2];
    const float* Wv    = (const float*)d_in[3];
    const float* Wo    = (const float*)d_in[4];
    const float* pitch = (const float*)d_in[5];
    float* out = (float*)d_out;

    // ws layout (f16 elements). o_buf aliases hs16 (hs16 dead after qkv_kernel).
    _Float16* hs16  = (_Float16*)d_ws;                           // M*512 = 3,145,728
    _Float16* o_buf = hs16;                                      // alias
    _Float16* q_buf = hs16 + (size_t)M_ * 512;                   // 3,145,728
    _Float16* k_buf = q_buf + (size_t)B_ * H_ * S_ * 64;         //   786,432
    _Float16* v_buf = k_buf + (size_t)B_ * HKV_ * S_ * 64;       //   786,432
    _Float16* wcatT = v_buf + (size_t)B_ * HKV_ * S_ * 64;       //   393,216
    _Float16* woT   = wcatT + (size_t)NQKV * 512;                //   262,144

    prep_kernel<<<352, 256, 0, stream>>>(hs, Wq, Wk, Wv, Wo, hs16, wcatT, woT);
    qkv_kernel<<<dim3(M_ / 64, NQKV / 64), 256, 0, stream>>>(hs16, wcatT, pitch, q_buf, k_buf, v_buf);
    attn_kernel<<<dim3(S_ / 64, B_ * H_), 512, 0, stream>>>(q_buf, k_buf, v_buf, o_buf);
    proj_out_kernel<<<dim3(M_ / 64, 8), 256, 0, stream>>>(o_buf, woT, out);
}